// Round 7
// baseline (198.880 us; speedup 1.0000x reference)
//
#include <hip/hip_runtime.h>

// YOLO-style loss, MI355X — round 7: instrumented probe round.
// loss = (2*sum((p_box - t_box)^2) + sum(mask ? CE : 0)) / 512
// channels: box = {0..3, 24..27}; cls = {8..27}; 4..7 unused.
//
// Round-6 finding: strided and staged kernels BOTH run ~90MB/28.4us ~= 3.1 TB/s
// (half of achievable). This round surfaces the kernel in rocprof's top-5:
//  - B_dummy: staged kernel over TWO cold 90MB pairs in ONE dispatch (180 MB).
//      BW-wall -> ~57us @3.2TB/s | per-launch overhead -> ~43us | healthy -> ~29us.
//  - A: plain float4 grid-stride read of the same 180 MB (L3-warm after B_dummy)
//      = read-BW ceiling probe; FETCH_SIZE shows whether L3 retained it.
//  - real pass: npairs=1 on (preds,tgts) — unchanged round-6 logic (absmax 0).

#define C_CLS 20
#define D_CH 28
#define BATCH_N 512
#define CELLS (BATCH_N * 28 * 28)     // 401408
#define BLOCK 256
#define CPB 256
#define NBLOCKS (CELLS / CPB)         // 1568
#define REG_FLOATS ((size_t)CELLS * D_CH)   // 11,239,424 floats = 44.96 MB

__global__ __launch_bounds__(BLOCK) void yolo_staged_kernel(
    const float* __restrict__ p0,
    const float* __restrict__ t0,
    long pairStride,               // floats between consecutive (p,t) pairs
    int npairs,
    float* __restrict__ out)
{
    __shared__ float ldsP[CPB * C_CLS];   // 20 KB
    __shared__ float ldsT[CPB * C_CLS];   // 20 KB
    __shared__ float sm[BLOCK / 64];

    const int tid = threadIdx.x;
    float loss = 0.0f;

    for (int q = 0; q < npairs; ++q) {
        const size_t off = (size_t)q * (size_t)pairStride
                         + (size_t)blockIdx.x * (CPB * D_CH);
        const float4* gp = reinterpret_cast<const float4*>(p0 + off);
        const float4* gt = reinterpret_cast<const float4*>(t0 + off);

        // coalesced: 7 float4/tensor/thread, lane stride 16 B
        float4 vp[7], vt[7];
        #pragma unroll
        for (int k = 0; k < 7; ++k) vp[k] = gp[tid + BLOCK * k];
        #pragma unroll
        for (int k = 0; k < 7; ++k) vt[k] = gt[tid + BLOCK * k];

        // coord inline (each thread owns one c4==0 and one c4==6 chunk)
        float coord = 0.0f;
        #pragma unroll
        for (int k = 0; k < 7; ++k) {
            const int c4 = (tid + BLOCK * k) % 7;
            if (c4 == 0 || c4 == 6) {
                float dx = vp[k].x - vt[k].x; coord = fmaf(dx, dx, coord);
                float dy = vp[k].y - vt[k].y; coord = fmaf(dy, dy, coord);
                float dz = vp[k].z - vt[k].z; coord = fmaf(dz, dz, coord);
                float dw = vp[k].w - vt[k].w; coord = fmaf(dw, dw, coord);
            }
        }

        // stage cls chunks (c4 in 2..6), packed 80B rows, one barrier
        #pragma unroll
        for (int k = 0; k < 7; ++k) {
            const int idx  = tid + BLOCK * k;
            const int cell = idx / 7;
            const int c4   = idx - cell * 7;
            if (c4 >= 2) {
                *reinterpret_cast<float4*>(&ldsP[cell * C_CLS + (c4 - 2) * 4]) = vp[k];
                *reinterpret_cast<float4*>(&ldsT[cell * C_CLS + (c4 - 2) * 4]) = vt[k];
            }
        }
        __syncthreads();

        float pc[C_CLS];
        #pragma unroll
        for (int s = 0; s < 5; ++s) {
            float4 a = *reinterpret_cast<const float4*>(&ldsP[tid * C_CLS + s * 4]);
            pc[4*s+0] = a.x; pc[4*s+1] = a.y; pc[4*s+2] = a.z; pc[4*s+3] = a.w;
        }
        float m = pc[0];
        #pragma unroll
        for (int j = 1; j < C_CLS; ++j) m = fmaxf(m, pc[j]);
        float se = 0.0f;
        #pragma unroll
        for (int j = 0; j < C_CLS; ++j) se += __expf(pc[j] - m);

        float tsum = 0.0f, tmax = -INFINITY;
        int lab = 0;
        #pragma unroll
        for (int s = 0; s < 5; ++s) {
            float4 a = *reinterpret_cast<const float4*>(&ldsT[tid * C_CLS + s * 4]);
            tsum += a.x + a.y + a.z + a.w;
            if (a.x > tmax) { tmax = a.x; lab = 4*s+0; }
            if (a.y > tmax) { tmax = a.y; lab = 4*s+1; }
            if (a.z > tmax) { tmax = a.z; lab = 4*s+2; }
            if (a.w > tmax) { tmax = a.w; lab = 4*s+3; }
        }
        float plab = pc[0];
        #pragma unroll
        for (int j = 1; j < C_CLS; ++j) plab = (lab == j) ? pc[j] : plab;
        float ce = -(plab - m - __logf(se));

        loss += 2.0f * coord + ((tsum > 0.0f) ? ce : 0.0f);
        __syncthreads();   // protect LDS reuse across pairs
    }

    // wave + block reduce, one atomic per block per dispatch
    #pragma unroll
    for (int off = 32; off > 0; off >>= 1) loss += __shfl_down(loss, off, 64);
    const int wid  = tid >> 6;
    const int lane = tid & 63;
    if (lane == 0) sm[wid] = loss;
    __syncthreads();
    if (tid == 0) {
        float s = sm[0] + sm[1] + sm[2] + sm[3];
        atomicAdd(out, s * (1.0f / (float)BATCH_N));
    }
}

// Pure streaming-read BW probe: sums 180 MB of float4s.
__global__ __launch_bounds__(BLOCK) void bw_read_kernel(
    const float4* __restrict__ src, float* __restrict__ sink)
{
    const size_t n4 = REG_FLOATS;          // 4 slabs * REG floats / 4 = REG float4s
    size_t i = (size_t)blockIdx.x * BLOCK + threadIdx.x;
    const size_t stride = (size_t)gridDim.x * BLOCK;
    float acc = 0.0f;
    for (; i < n4; i += stride) {
        float4 v = src[i];
        acc += v.x + v.y + v.z + v.w;
    }
    #pragma unroll
    for (int off = 32; off > 0; off >>= 1) acc += __shfl_down(acc, off, 64);
    __shared__ float sm[BLOCK / 64];
    const int wid  = threadIdx.x >> 6;
    const int lane = threadIdx.x & 63;
    if (lane == 0) sm[wid] = acc;
    __syncthreads();
    if (threadIdx.x == 0) atomicAdd(sink, sm[0] + sm[1] + sm[2] + sm[3]);
}

extern "C" void kernel_launch(void* const* d_in, const int* in_sizes, int n_in,
                              void* d_out, int out_size, void* d_ws, size_t ws_size,
                              hipStream_t stream)
{
    const float* preds = (const float*)d_in[0];
    const float* tgts  = (const float*)d_in[1];
    float* out = (float*)d_out;
    float* ws  = (float*)d_ws;

    hipMemsetAsync(out, 0, (size_t)out_size * sizeof(float), stream);

    // probes over 4 cold 45MB ws slabs (0xAA poison decodes to -3e-13: finite,
    // tsum<0 masks CE). Guarded by ws capacity; sinks placed past the slabs.
    const size_t need = (4 * REG_FLOATS + 64) * sizeof(float);
    if (ws_size >= need) {
        float* sinkA = ws + 4 * REG_FLOATS;
        float* sinkB = sinkA + 16;
        // B_dummy: staged kernel, TWO cold pairs in one dispatch (180 MB)
        yolo_staged_kernel<<<NBLOCKS, BLOCK, 0, stream>>>(
            ws, ws + REG_FLOATS, (long)(2 * REG_FLOATS), 2, sinkB);
        // A: plain streaming read of the same 180 MB (now L3-warm if L3 retains)
        bw_read_kernel<<<2048, BLOCK, 0, stream>>>(
            reinterpret_cast<const float4*>(ws), sinkA);
    }

    // real pass
    yolo_staged_kernel<<<NBLOCKS, BLOCK, 0, stream>>>(preds, tgts, 0L, 1, out);
}